// Round 2
// baseline (1260.975 us; speedup 1.0000x reference)
//
#include <hip/hip_runtime.h>

// CFA channel-attention, B=2, C=512, H=W=128, HEADS=4, gfx950.
// f32 in/out; internal fp16 MFMA + f32 accumulation.
// Per-batch pipeline; ws footprint 71 MB; kv_pre staged inside d_out.
//
// ws layout (bytes from base):
//   A  [ 0,16M)  : xc (fp16 cast of x)  -> q after dwconv
//   B  [16,32M)  : xT [N][512]          -> vT after transpose_v
//   C  [32,48M)  : yT [N][512]          -> v after dwconv
//   D  [48,64M)  : q_pre [512][N]       -> k after dwconv
//   SM [64,71M)  : G(2M) lgs(512K) n2q/n2k/srow | bq/bk/tq/tk | Wq(512K)
//                  Wkv(1M) | PqG(1M) | lgp(256K) comb(256K) Mb(512K)

typedef _Float16 f16_t;
typedef __attribute__((ext_vector_type(8))) _Float16 f16x8;
typedef __attribute__((ext_vector_type(4))) float f32x4;

#define NDIM 16384

__device__ __forceinline__ void gload_lds16(const void* g, void* l) {
  __builtin_amdgcn_global_load_lds((__attribute__((address_space(1))) void*)g,
                                   (__attribute__((address_space(3))) void*)l, 16, 0, 0);
}

// C = A * B^T ; A [M,K] row-major f16, B [Ncols,K] row-major f16. 128x128 tile,
// 4 waves 2x2, each 64x64 via 4x4 mfma_f32_16x16x32_f16.
// EPI: 0 = store f16, 1 = store f32, 2 = atomicAdd f32 (split-K).
template<int EPI>
__device__ __forceinline__ void gemm_core_128(
    const f16_t* __restrict__ At, int lda,
    const f16_t* __restrict__ Bt, int ldb,
    void* __restrict__ Ct, int ldc, int K)
{
  __shared__ f16_t As[128 * 32];
  __shared__ f16_t Bs[128 * 32];
  const int tid = threadIdx.x;
  const int lane = tid & 63;
  const int wave = tid >> 6;
  const int wm = (wave >> 1) * 64;
  const int wn = (wave & 1) * 64;
  const int lr = lane & 15;
  const int lq = lane >> 4;

  const f16_t* gA0 = At + (size_t)(tid >> 2) * lda + (tid & 3) * 8;
  const f16_t* gA1 = At + (size_t)((tid + 256) >> 2) * lda + (tid & 3) * 8;
  const f16_t* gB0 = Bt + (size_t)(tid >> 2) * ldb + (tid & 3) * 8;
  const f16_t* gB1 = Bt + (size_t)((tid + 256) >> 2) * ldb + (tid & 3) * 8;
  f16_t* lA0 = &As[tid * 8];
  f16_t* lA1 = &As[(tid + 256) * 8];
  f16_t* lB0 = &Bs[tid * 8];
  f16_t* lB1 = &Bs[(tid + 256) * 8];

  f32x4 acc[4][4] = {};

  for (int kk = 0; kk < K; kk += 32) {
    if (kk) __syncthreads();
    gload_lds16(gA0 + kk, lA0);
    gload_lds16(gA1 + kk, lA1);
    gload_lds16(gB0 + kk, lB0);
    gload_lds16(gB1 + kk, lB1);
    __syncthreads();

    f16x8 af[4], bfr[4];
#pragma unroll
    for (int i = 0; i < 4; i++) {
      af[i]  = *(const f16x8*)&As[(wm + i * 16 + lr) * 32 + lq * 8];
      bfr[i] = *(const f16x8*)&Bs[(wn + i * 16 + lr) * 32 + lq * 8];
    }
#pragma unroll
    for (int i = 0; i < 4; i++)
#pragma unroll
      for (int j = 0; j < 4; j++)
        acc[i][j] = __builtin_amdgcn_mfma_f32_16x16x32_f16(af[i], bfr[j], acc[i][j], 0, 0, 0);
  }

  // C/D layout: col = lane&15, row = (lane>>4)*4 + reg   [m89-verified]
#pragma unroll
  for (int i = 0; i < 4; i++)
#pragma unroll
    for (int j = 0; j < 4; j++)
#pragma unroll
      for (int r = 0; r < 4; r++) {
        int row = wm + i * 16 + lq * 4 + r;
        int col = wn + j * 16 + lr;
        float v = acc[i][j][r];
        if (EPI == 0)      ((f16_t*)Ct)[(size_t)row * ldc + col] = (f16_t)v;
        else if (EPI == 1) ((float*)Ct)[(size_t)row * ldc + col] = v;
        else               atomicAdd(&((float*)Ct)[(size_t)row * ldc + col], v);
      }
}

template<int EPI, typename CT>
__global__ __launch_bounds__(256) void gemm_bt_kernel(
    const f16_t* __restrict__ A, int lda, const f16_t* __restrict__ B, int ldb,
    CT* __restrict__ C, int ldc, int K)
{
  const f16_t* At = A + (size_t)blockIdx.y * 128 * lda;
  const f16_t* Bt = B + (size_t)blockIdx.x * 128 * ldb;
  CT* Ct = C + (size_t)blockIdx.y * 128 * ldc + (size_t)blockIdx.x * 128;
  gemm_core_128<EPI>(At, lda, Bt, ldb, (void*)Ct, ldc, K);
}

// Gram: G += xc * xc^T, split-K 16x1024, grid (16 ks, 16 tiles)
__global__ __launch_bounds__(256) void gram_kernel(
    const f16_t* __restrict__ xc, float* __restrict__ Gb)
{
  int ks = blockIdx.x, t = blockIdx.y;
  int ty = t >> 2, tx = t & 3;
  const f16_t* At = xc + (size_t)ty * 128 * NDIM + ks * 1024;
  const f16_t* Bt = xc + (size_t)tx * 128 * NDIM + ks * 1024;
  float* Ct = Gb + (size_t)ty * 128 * 512 + tx * 128;
  gemm_core_128<2>(At, NDIM, Bt, NDIM, Ct, 512, 1024);
}

// S-branch raw QK^T, split-K=64 (K=256 each), grid (64 ks, 4 h)
__global__ __launch_bounds__(256) void qk_kernel(
    const f16_t* __restrict__ q, const f16_t* __restrict__ k,
    float* __restrict__ lgs_b)
{
  int ks = blockIdx.x, h = blockIdx.y;
  const f16_t* At = q + (size_t)h * 128 * NDIM + ks * 256;
  const f16_t* Bt = k + (size_t)h * 128 * NDIM + ks * 256;
  float* Ct = lgs_b + (size_t)h * 16384;
  gemm_core_128<2>(At, NDIM, Bt, NDIM, Ct, 128, 256);
}

// two f32 [512][NDIM] sources -> f16 [NDIM][512] transposed; z selects pair
__global__ __launch_bounds__(256) void transpose2_kernel(
    const float* __restrict__ sx, const float* __restrict__ sy,
    f16_t* __restrict__ dx, f16_t* __restrict__ dy)
{
  const float* src = blockIdx.z ? sy : sx;
  f16_t* dst = blockIdx.z ? dy : dx;
  __shared__ f16_t tile[32][33];
  int tx = threadIdx.x & 31, ty = threadIdx.x >> 5;
  int r0 = blockIdx.y * 32, c0 = blockIdx.x * 32;
#pragma unroll
  for (int k = 0; k < 4; k++) {
    int r = ty + k * 8;
    tile[r][tx] = (f16_t)src[(size_t)(r0 + r) * NDIM + c0 + tx];
  }
  __syncthreads();
#pragma unroll
  for (int k = 0; k < 4; k++) {
    int r = ty + k * 8;
    dst[(size_t)(c0 + r) * 512 + r0 + tx] = tile[tx][r];
  }
}

// f16 [512][NDIM] -> f16 [NDIM][512]
__global__ __launch_bounds__(256) void transpose_f16_kernel(
    const f16_t* __restrict__ src, f16_t* __restrict__ dst)
{
  __shared__ f16_t tile[32][33];
  int tx = threadIdx.x & 31, ty = threadIdx.x >> 5;
  int r0 = blockIdx.y * 32, c0 = blockIdx.x * 32;
#pragma unroll
  for (int k = 0; k < 4; k++) {
    int r = ty + k * 8;
    tile[r][tx] = src[(size_t)(r0 + r) * NDIM + c0 + tx];
  }
  __syncthreads();
#pragma unroll
  for (int k = 0; k < 4; k++) {
    int r = ty + k * 8;
    dst[(size_t)(c0 + r) * 512 + r0 + tx] = tile[tx][r];
  }
}

// x (f32 [512][N]) -> xc (f16) + fused row sums (atomic). grid (64, 512)
__global__ __launch_bounds__(256) void cast_x_kernel(
    const float* __restrict__ xb, f16_t* __restrict__ xc, float* __restrict__ srow_b)
{
  int c = blockIdx.y;
  int n = blockIdx.x * 256 + threadIdx.x;
  float v = xb[(size_t)c * NDIM + n];
  xc[(size_t)c * NDIM + n] = (f16_t)v;
  __shared__ float red[256];
  red[threadIdx.x] = v;
  __syncthreads();
  for (int s = 128; s > 0; s >>= 1) {
    if (threadIdx.x < s) red[threadIdx.x] += red[threadIdx.x + s];
    __syncthreads();
  }
  if (threadIdx.x == 0) atomicAdd(&srow_b[c], red[0]);
}

// depthwise 3x3 SAME + optional fused sum-of-squares (atomic). grid (64, C)
__global__ __launch_bounds__(256) void dwconv_kernel(
    const f16_t* __restrict__ in, const float* __restrict__ w,
    f16_t* __restrict__ outA, f16_t* __restrict__ outB,
    int splitC, float* __restrict__ norm2)
{
  int c = blockIdx.y;
  int n = blockIdx.x * 256 + threadIdx.x;
  const f16_t* src = in + (size_t)c * NDIM;
  const float* wc = w + c * 9;
  int h = n >> 7, x = n & 127;
  float a = 0.f;
#pragma unroll
  for (int dh = -1; dh <= 1; dh++) {
    int hh = h + dh;
    if (hh < 0 || hh > 127) continue;
#pragma unroll
    for (int dw = -1; dw <= 1; dw++) {
      int xx = x + dw;
      if (xx < 0 || xx > 127) continue;
      a += wc[(dh + 1) * 3 + (dw + 1)] * (float)src[hh * 128 + xx];
    }
  }
  if (c < splitC) {
    outA[(size_t)c * NDIM + n] = (f16_t)a;
    __shared__ float red[256];
    red[threadIdx.x] = a * a;
    __syncthreads();
    for (int s = 128; s > 0; s >>= 1) {
      if (threadIdx.x < s) red[threadIdx.x] += red[threadIdx.x + s];
      __syncthreads();
    }
    if (threadIdx.x == 0) atomicAdd(&norm2[c], red[0]);
  } else {
    outB[(size_t)(c - splitC) * NDIM + n] = (f16_t)a;
  }
}

// bq = Pq@pe, bk = Pk@pe, tq = Pq@srow, tk = Pk@srow. grid (512 o, 4 which)
__global__ __launch_bounds__(64) void vec4_kernel(
    const float* __restrict__ pqw, const float* __restrict__ pkw,
    const float* __restrict__ pe, const float* __restrict__ srow_b,
    float* __restrict__ bq, float* __restrict__ bk,
    float* __restrict__ tq_b, float* __restrict__ tk_b)
{
  int o = blockIdx.x, which = blockIdx.y, lane = threadIdx.x;
  const float* w = ((which & 1) == 0) ? pqw + (size_t)o * 512 : pkw + (size_t)o * 512;
  const float* v = (which < 2) ? pe : srow_b;
  float s = 0.f;
  for (int c = lane; c < 512; c += 64) s += w[c] * v[c];
#pragma unroll
  for (int off = 32; off > 0; off >>= 1) s += __shfl_down(s, off, 64);
  if (lane == 0) {
    float* dst = (which == 0) ? bq : (which == 1) ? bk : (which == 2) ? tq_b : tk_b;
    dst[o] = s;
  }
}

// PqG[h][r][d] = sum_c Pq[h*128+r,c] * G[c,d]. grid (32 dt, 8 rt, 4 h)
__global__ __launch_bounds__(256) void posA_kernel(
    const float* __restrict__ pqw, const float* __restrict__ Gb,
    float* __restrict__ PqG)
{
  int tx = threadIdx.x & 15, ty = threadIdx.x >> 4;
  int h = blockIdx.z;
  int r = blockIdx.y * 16 + ty;
  int d = blockIdx.x * 16 + tx;
  const float* wr = pqw + (size_t)(h * 128 + r) * 512;
  float s = 0.f;
#pragma unroll 4
  for (int c = 0; c < 512; c++) s += wr[c] * Gb[(size_t)c * 512 + d];
  PqG[((size_t)h * 128 + r) * 512 + d] = s;
}

// lgp[h][r][s] = PqG[h,r,:]·Pk[h*128+s,:] + tq*bk + bq*tk + N*bq*bk
__global__ __launch_bounds__(256) void posB_kernel(
    const float* __restrict__ PqG, const float* __restrict__ pkw,
    const float* __restrict__ bq, const float* __restrict__ bk,
    const float* __restrict__ tq_b, const float* __restrict__ tk_b,
    float* __restrict__ lgp)
{
  int tx = threadIdx.x & 15, ty = threadIdx.x >> 4;
  int h = blockIdx.z;
  int r = blockIdx.y * 16 + ty;
  int s = blockIdx.x * 16 + tx;
  int gr = h * 128 + r, gs = h * 128 + s;
  const float* ar = PqG + (size_t)gr * 512;
  const float* kr = pkw + (size_t)gs * 512;
  float acc = 0.f;
#pragma unroll 4
  for (int c = 0; c < 512; c++) acc += ar[c] * kr[c];
  acc += tq_b[gr] * bk[gs] + bq[gr] * tk_b[gs] + 16384.f * bq[gr] * bk[gs];
  lgp[(size_t)h * 16384 + r * 128 + s] = acc;
}

// comb = softmax(lgs/(rq*rk)*t) + softmax(lgp). grid 512 (h,c), 128 thr (d)
__global__ __launch_bounds__(128) void smx_kernel(
    const float* __restrict__ lgs_b, const float* __restrict__ lgp,
    const float* __restrict__ n2q_b, const float* __restrict__ n2k_b,
    const float* __restrict__ temp, float* __restrict__ comb)
{
  int c = blockIdx.x & 127, h = blockIdx.x >> 7;
  int d = threadIdx.x;
  float rq = fmaxf(sqrtf(n2q_b[h * 128 + c]), 1e-12f);
  float rk = fmaxf(sqrtf(n2k_b[h * 128 + d]), 1e-12f);
  float s0 = lgs_b[(size_t)h * 16384 + c * 128 + d] / (rq * rk) * temp[h];
  float s1 = lgp[(size_t)h * 16384 + c * 128 + d];
  __shared__ float sh[128];
  sh[d] = s0; __syncthreads();
  for (int s = 64; s > 0; s >>= 1) { if (d < s) sh[d] = fmaxf(sh[d], sh[d + s]); __syncthreads(); }
  float m0 = sh[0]; __syncthreads();
  float e0 = __expf(s0 - m0);
  sh[d] = e0; __syncthreads();
  for (int s = 64; s > 0; s >>= 1) { if (d < s) sh[d] += sh[d + s]; __syncthreads(); }
  float z0 = sh[0]; __syncthreads();
  sh[d] = s1; __syncthreads();
  for (int s = 64; s > 0; s >>= 1) { if (d < s) sh[d] = fmaxf(sh[d], sh[d + s]); __syncthreads(); }
  float m1 = sh[0]; __syncthreads();
  float e1 = __expf(s1 - m1);
  sh[d] = e1; __syncthreads();
  for (int s = 64; s > 0; s >>= 1) { if (d < s) sh[d] += sh[d + s]; __syncthreads(); }
  float z1 = sh[0];
  comb[(size_t)h * 16384 + c * 128 + d] = e0 / z0 + e1 / z1;
}

// Mb[o][h*128+d] = sum_r proj_w[o, h*128+r] * comb[h][r][d]. grid (8,32,4)
__global__ __launch_bounds__(256) void mb_kernel(
    const float* __restrict__ proj_w, const float* __restrict__ comb,
    f16_t* __restrict__ Mb)
{
  int tx = threadIdx.x & 15, ty = threadIdx.x >> 4;
  int h = blockIdx.z;
  int o = blockIdx.y * 16 + ty;
  int d = blockIdx.x * 16 + tx;
  const float* pw = proj_w + (size_t)o * 512 + h * 128;
  const float* cm = comb + (size_t)h * 16384 + d;
  float s = 0.f;
#pragma unroll 4
  for (int r = 0; r < 128; r++) s += pw[r] * cm[(size_t)r * 128];
  Mb[(size_t)o * 512 + h * 128 + d] = (f16_t)s;
}

__global__ __launch_bounds__(256) void castw_kernel(
    const float* __restrict__ q_w, const float* __restrict__ kv_w,
    f16_t* __restrict__ Wq, f16_t* __restrict__ Wkv)
{
  int i = blockIdx.x * 256 + threadIdx.x;
  if (i < 262144) Wq[i] = (f16_t)q_w[i];
  else Wkv[i - 262144] = (f16_t)kv_w[i - 262144];
}

__global__ __launch_bounds__(256) void zero_kernel(float* __restrict__ p, long n) {
  long i = (long)blockIdx.x * 256 + threadIdx.x;
  if (i < n) p[i] = 0.f;
}

extern "C" void kernel_launch(void* const* d_in, const int* in_sizes, int n_in,
                              void* d_out, int out_size, void* d_ws, size_t ws_size,
                              hipStream_t stream) {
  const float* x      = (const float*)d_in[0];
  const float* y      = (const float*)d_in[1];
  const float* temp   = (const float*)d_in[2];
  const float* q_w    = (const float*)d_in[3];
  const float* q_dw   = (const float*)d_in[4];
  const float* kv_w   = (const float*)d_in[5];
  const float* kv_dw  = (const float*)d_in[6];
  const float* proj_w = (const float*)d_in[7];
  const float* pe     = (const float*)d_in[8];
  const float* pqw    = (const float*)d_in[9];
  const float* pkw    = (const float*)d_in[10];

  const size_t MB = 1ull << 20;
  const size_t N = NDIM;
  char* Wb = (char*)d_ws;
  f16_t* Abuf = (f16_t*)(Wb);             // xc -> q
  f16_t* Bbuf = (f16_t*)(Wb + 16 * MB);   // xT -> vT
  f16_t* Cbuf = (f16_t*)(Wb + 32 * MB);   // yT -> v
  f16_t* Dbuf = (f16_t*)(Wb + 48 * MB);   // q_pre -> k
  char* SM = Wb + 64 * MB;
  float* G    = (float*)(SM);                       // [2][512][512]
  float* lgs  = (float*)(SM + 2 * MB);              // [2][4][16384]
  float* n2q  = (float*)(SM + 2 * MB + 512 * 1024); // [2][512]
  float* n2k  = n2q + 1024;
  float* srow = n2k + 1024;                         // [2][512]
  float* bq   = (float*)(SM + 3 * MB);
  float* bk   = bq + 512;
  float* tq   = bk + 512;                           // [2][512]
  float* tk   = tq + 1024;
  f16_t* Wq   = (f16_t*)(SM + 3 * MB + 16 * 1024);
  f16_t* Wkv  = (f16_t*)(SM + 3 * MB + 16 * 1024 + 512 * 1024);
  float* PqG  = (float*)(SM + 5 * MB);              // [4][128][512]
  float* lgp  = (float*)(SM + 6 * MB);              // [4][16384]
  float* comb = (float*)(SM + 6 * MB + 256 * 1024); // [4][16384]
  f16_t* Mb   = (f16_t*)(SM + 6 * MB + 512 * 1024); // [512][512]
  // total ws use: 71 MB

  // zero atomic targets: G, lgs, n2q, n2k, srow  (2.5 MB + 12 KB)
  zero_kernel<<<2572, 256, 0, stream>>>((float*)SM, 658432L);
  castw_kernel<<<3072, 256, 0, stream>>>(q_w, kv_w, Wq, Wkv);

  for (int b = 0; b < 2; b++) {
    const float* xb = x + (size_t)b * 512 * N;
    const float* yb = y + (size_t)b * 512 * N;
    float* srow_b = srow + b * 512;
    float* Gb = G + (size_t)b * 512 * 512;
    float* lgs_b = lgs + (size_t)b * 4 * 16384;
    f16_t* kvp = (f16_t*)d_out + (size_t)b * 1024 * N;   // scratch in d_out
    float* outb = (float*)d_out + (size_t)b * 512 * N;

    cast_x_kernel<<<dim3(64, 512), 256, 0, stream>>>(xb, Abuf, srow_b);
    vec4_kernel<<<dim3(512, 4), 64, 0, stream>>>(pqw, pkw, pe, srow_b,
                                                 bq, bk, tq + b * 512, tk + b * 512);
    gram_kernel<<<dim3(16, 16), 256, 0, stream>>>(Abuf, Gb);
    transpose2_kernel<<<dim3(512, 16, 2), 256, 0, stream>>>(xb, yb, Bbuf, Cbuf);
    // q_pre = Wq @ xT^T
    gemm_bt_kernel<0, f16_t><<<dim3(128, 4), 256, 0, stream>>>(
        Wq, 512, Bbuf, 512, Dbuf, (int)N, 512);
    // kv_pre = Wkv @ yT^T  (staged in d_out)
    gemm_bt_kernel<0, f16_t><<<dim3(128, 8), 256, 0, stream>>>(
        Wkv, 512, Cbuf, 512, kvp, (int)N, 512);
    // dwconv q (+||q row||^2), q -> Abuf (xc dead after gram)
    dwconv_kernel<<<dim3(64, 512), 256, 0, stream>>>(
        Dbuf, q_dw, Abuf, (f16_t*)nullptr, 512, n2q + b * 512);
    // dwconv kv: k -> Dbuf (q_pre dead), v -> Cbuf (yT dead)
    dwconv_kernel<<<dim3(64, 1024), 256, 0, stream>>>(
        kvp, kv_dw, Dbuf, Cbuf, 512, n2k + b * 512);
    // vT -> Bbuf (xT dead)
    transpose_f16_kernel<<<dim3(512, 16), 256, 0, stream>>>(Cbuf, Bbuf);
    // S-branch raw logits
    qk_kernel<<<dim3(64, 4), 256, 0, stream>>>(Abuf, Dbuf, lgs_b);
    // pos branch via Gram
    posA_kernel<<<dim3(32, 8, 4), 256, 0, stream>>>(pqw, Gb, PqG);
    posB_kernel<<<dim3(8, 8, 4), 256, 0, stream>>>(PqG, pkw, bq, bk,
                                                   tq + b * 512, tk + b * 512, lgp);
    smx_kernel<<<512, 128, 0, stream>>>(lgs_b, lgp, n2q + b * 512, n2k + b * 512,
                                        temp, comb);
    mb_kernel<<<dim3(8, 32, 4), 256, 0, stream>>>(proj_w, comb, Mb);
    // out_b = Mb @ vT^T  (overwrites kvp region, which is dead)
    gemm_bt_kernel<1, float><<<dim3(128, 4), 256, 0, stream>>>(
        Mb, 512, Bbuf, 512, outb, (int)N, 512);
  }

  (void)in_sizes; (void)n_in; (void)out_size; (void)ws_size;
}

// Round 3
// 797.256 us; speedup vs baseline: 1.5816x; 1.5816x over previous
//
#include <hip/hip_runtime.h>

// CFA channel-attention, B=2, C=512, H=W=128, HEADS=4, gfx950.
// f32 in/out; internal fp16 MFMA + f32 accumulation.
// Per-batch pipeline; ws footprint 71 MB; kv_pre staged inside d_out.

typedef _Float16 f16_t;
typedef __attribute__((ext_vector_type(8))) _Float16 f16x8;
typedef __attribute__((ext_vector_type(4))) float f32x4;

#define NDIM 16384

__device__ __forceinline__ void gload_lds16(const void* g, void* l) {
  __builtin_amdgcn_global_load_lds((__attribute__((address_space(1))) void*)g,
                                   (__attribute__((address_space(3))) void*)l, 16, 0, 0);
}

// C = A * B^T ; A [M,K] row-major f16, B [Ncols,K] row-major f16. 128x128 tile,
// 4 waves 2x2, each 64x64 via 4x4 mfma_f32_16x16x32_f16.
// EPI: 0 = store f16, 1 = store f32, 2 = atomicAdd f32 (split-K).
template<int EPI>
__device__ __forceinline__ void gemm_core_128(
    const f16_t* __restrict__ At, int lda,
    const f16_t* __restrict__ Bt, int ldb,
    void* __restrict__ Ct, int ldc, int K)
{
  __shared__ f16_t As[128 * 32];
  __shared__ f16_t Bs[128 * 32];
  const int tid = threadIdx.x;
  const int lane = tid & 63;
  const int wave = tid >> 6;
  const int wm = (wave >> 1) * 64;
  const int wn = (wave & 1) * 64;
  const int lr = lane & 15;
  const int lq = lane >> 4;

  const f16_t* gA0 = At + (size_t)(tid >> 2) * lda + (tid & 3) * 8;
  const f16_t* gA1 = At + (size_t)((tid + 256) >> 2) * lda + (tid & 3) * 8;
  const f16_t* gB0 = Bt + (size_t)(tid >> 2) * ldb + (tid & 3) * 8;
  const f16_t* gB1 = Bt + (size_t)((tid + 256) >> 2) * ldb + (tid & 3) * 8;
  f16_t* lA0 = &As[tid * 8];
  f16_t* lA1 = &As[(tid + 256) * 8];
  f16_t* lB0 = &Bs[tid * 8];
  f16_t* lB1 = &Bs[(tid + 256) * 8];

  f32x4 acc[4][4] = {};

  for (int kk = 0; kk < K; kk += 32) {
    if (kk) __syncthreads();
    gload_lds16(gA0 + kk, lA0);
    gload_lds16(gA1 + kk, lA1);
    gload_lds16(gB0 + kk, lB0);
    gload_lds16(gB1 + kk, lB1);
    __syncthreads();

    f16x8 af[4], bfr[4];
#pragma unroll
    for (int i = 0; i < 4; i++) {
      af[i]  = *(const f16x8*)&As[(wm + i * 16 + lr) * 32 + lq * 8];
      bfr[i] = *(const f16x8*)&Bs[(wn + i * 16 + lr) * 32 + lq * 8];
    }
#pragma unroll
    for (int i = 0; i < 4; i++)
#pragma unroll
      for (int j = 0; j < 4; j++)
        acc[i][j] = __builtin_amdgcn_mfma_f32_16x16x32_f16(af[i], bfr[j], acc[i][j], 0, 0, 0);
  }

  // C/D layout: col = lane&15, row = (lane>>4)*4 + reg   [m89-verified]
#pragma unroll
  for (int i = 0; i < 4; i++)
#pragma unroll
    for (int j = 0; j < 4; j++)
#pragma unroll
      for (int r = 0; r < 4; r++) {
        int row = wm + i * 16 + lq * 4 + r;
        int col = wn + j * 16 + lr;
        float v = acc[i][j][r];
        if (EPI == 0)      ((f16_t*)Ct)[(size_t)row * ldc + col] = (f16_t)v;
        else if (EPI == 1) ((float*)Ct)[(size_t)row * ldc + col] = v;
        else               atomicAdd(&((float*)Ct)[(size_t)row * ldc + col], v);
      }
}

template<int EPI, typename CT>
__global__ __launch_bounds__(256) void gemm_bt_kernel(
    const f16_t* __restrict__ A, int lda, const f16_t* __restrict__ B, int ldb,
    CT* __restrict__ C, int ldc, int K)
{
  const f16_t* At = A + (size_t)blockIdx.y * 128 * lda;
  const f16_t* Bt = B + (size_t)blockIdx.x * 128 * ldb;
  CT* Ct = C + (size_t)blockIdx.y * 128 * ldc + (size_t)blockIdx.x * 128;
  gemm_core_128<EPI>(At, lda, Bt, ldb, (void*)Ct, ldc, K);
}

// Gram: G += xc * xc^T, split-K 16x1024, grid (16 ks, 16 tiles)
__global__ __launch_bounds__(256) void gram_kernel(
    const f16_t* __restrict__ xc, float* __restrict__ Gb)
{
  int ks = blockIdx.x, t = blockIdx.y;
  int ty = t >> 2, tx = t & 3;
  const f16_t* At = xc + (size_t)ty * 128 * NDIM + ks * 1024;
  const f16_t* Bt = xc + (size_t)tx * 128 * NDIM + ks * 1024;
  float* Ct = Gb + (size_t)ty * 128 * 512 + tx * 128;
  gemm_core_128<2>(At, NDIM, Bt, NDIM, Ct, 512, 1024);
}

// S-branch raw QK^T, split-K=32 (K=512 each), grid (32 ks, 4 h)
__global__ __launch_bounds__(256) void qk_kernel(
    const f16_t* __restrict__ q, const f16_t* __restrict__ k,
    float* __restrict__ lgs_b)
{
  int ks = blockIdx.x, h = blockIdx.y;
  const f16_t* At = q + (size_t)h * 128 * NDIM + ks * 512;
  const f16_t* Bt = k + (size_t)h * 128 * NDIM + ks * 512;
  float* Ct = lgs_b + (size_t)h * 16384;
  gemm_core_128<2>(At, NDIM, Bt, NDIM, Ct, 128, 512);
}

// two f32 [512][NDIM] sources -> f16 [NDIM][512] transposed; z selects pair
__global__ __launch_bounds__(256) void transpose2_kernel(
    const float* __restrict__ sx, const float* __restrict__ sy,
    f16_t* __restrict__ dx, f16_t* __restrict__ dy)
{
  const float* src = blockIdx.z ? sy : sx;
  f16_t* dst = blockIdx.z ? dy : dx;
  __shared__ f16_t tile[32][33];
  int tx = threadIdx.x & 31, ty = threadIdx.x >> 5;
  int r0 = blockIdx.y * 32, c0 = blockIdx.x * 32;
#pragma unroll
  for (int k = 0; k < 4; k++) {
    int r = ty + k * 8;
    tile[r][tx] = (f16_t)src[(size_t)(r0 + r) * NDIM + c0 + tx];
  }
  __syncthreads();
#pragma unroll
  for (int k = 0; k < 4; k++) {
    int r = ty + k * 8;
    dst[(size_t)(c0 + r) * 512 + r0 + tx] = tile[tx][r];
  }
}

// f16 [512][NDIM] -> f16 [NDIM][512]
__global__ __launch_bounds__(256) void transpose_f16_kernel(
    const f16_t* __restrict__ src, f16_t* __restrict__ dst)
{
  __shared__ f16_t tile[32][33];
  int tx = threadIdx.x & 31, ty = threadIdx.x >> 5;
  int r0 = blockIdx.y * 32, c0 = blockIdx.x * 32;
#pragma unroll
  for (int k = 0; k < 4; k++) {
    int r = ty + k * 8;
    tile[r][tx] = src[(size_t)(r0 + r) * NDIM + c0 + tx];
  }
  __syncthreads();
#pragma unroll
  for (int k = 0; k < 4; k++) {
    int r = ty + k * 8;
    dst[(size_t)(c0 + r) * 512 + r0 + tx] = tile[tx][r];
  }
}

// x (f32 [512][N]) -> xc (f16) + fused row sums (atomic). grid (64, 512)
__global__ __launch_bounds__(256) void cast_x_kernel(
    const float* __restrict__ xb, f16_t* __restrict__ xc, float* __restrict__ srow_b)
{
  int c = blockIdx.y;
  int n = blockIdx.x * 256 + threadIdx.x;
  float v = xb[(size_t)c * NDIM + n];
  xc[(size_t)c * NDIM + n] = (f16_t)v;
  __shared__ float red[256];
  red[threadIdx.x] = v;
  __syncthreads();
  for (int s = 128; s > 0; s >>= 1) {
    if (threadIdx.x < s) red[threadIdx.x] += red[threadIdx.x + s];
    __syncthreads();
  }
  if (threadIdx.x == 0) atomicAdd(&srow_b[c], red[0]);
}

// Depthwise 3x3 SAME, register-tiled + vectorized.
// grid (2 row-halves, C). Block 256 thr: thread t owns 8-wide x-strip
// ((t&15)*8) x 4 rows (hb*64 + (t>>4)*4). Loads 6 rows as f16x8 (16B),
// x-halo via intra-wave shfl (uniform execution, clamped row index).
// c < splitC -> outA (+ fused sum-of-squares into norm2, 2 atomics/channel),
// else -> outB.
__global__ __launch_bounds__(256) void dwconv_kernel(
    const f16_t* __restrict__ in, const float* __restrict__ w,
    f16_t* __restrict__ outA, f16_t* __restrict__ outB,
    int splitC, float* __restrict__ norm2)
{
  const int c = blockIdx.y;
  const int t = threadIdx.x;
  const int xs = (t & 15) * 8;
  const int h0 = blockIdx.x * 64 + (t >> 4) * 4;
  const f16_t* src = in + (size_t)c * NDIM;
  const float* wc = w + c * 9;
  float w00 = wc[0], w01 = wc[1], w02 = wc[2];
  float w10 = wc[3], w11 = wc[4], w12 = wc[5];
  float w20 = wc[6], w21 = wc[7], w22 = wc[8];

  // rows[i] = source row h0-1+i, as [left, v0..v7, right] in f32
  float rows[6][10];
#pragma unroll
  for (int i = 0; i < 6; i++) {
    int hh = h0 - 1 + i;
    int hc = hh < 0 ? 0 : (hh > 127 ? 127 : hh);
    f16x8 v = *(const f16x8*)(src + hc * 128 + xs);
    float l = __shfl_up((float)v[7], 1, 64);    // uniform: all lanes execute
    float r = __shfl_down((float)v[0], 1, 64);
    if ((t & 15) == 0) l = 0.f;
    if ((t & 15) == 15) r = 0.f;
    bool oob = (hh < 0) || (hh > 127);
    rows[i][0] = oob ? 0.f : l;
    rows[i][9] = oob ? 0.f : r;
#pragma unroll
    for (int j = 0; j < 8; j++) rows[i][1 + j] = oob ? 0.f : (float)v[j];
  }

  float s2 = 0.f;
  f16_t* dst = (c < splitC) ? outA + (size_t)c * NDIM
                            : outB + (size_t)(c - splitC) * NDIM;
#pragma unroll
  for (int i = 0; i < 4; i++) {
    f16x8 o;
#pragma unroll
    for (int j = 0; j < 8; j++) {
      float a = w00 * rows[i][j]     + w01 * rows[i][j + 1]     + w02 * rows[i][j + 2]
              + w10 * rows[i + 1][j] + w11 * rows[i + 1][j + 1] + w12 * rows[i + 1][j + 2]
              + w20 * rows[i + 2][j] + w21 * rows[i + 2][j + 1] + w22 * rows[i + 2][j + 2];
      o[j] = (f16_t)a;
      s2 += a * a;
    }
    *(f16x8*)(dst + (h0 + i) * 128 + xs) = o;
  }

  if (c < splitC) {
    __shared__ float red[256];
    red[t] = s2;
    __syncthreads();
    for (int s = 128; s > 0; s >>= 1) {
      if (t < s) red[t] += red[t + s];
      __syncthreads();
    }
    if (t == 0) atomicAdd(&norm2[c], red[0]);
  }
}

// bq = Pq@pe, bk = Pk@pe, tq = Pq@srow, tk = Pk@srow. grid (512 o, 4 which)
__global__ __launch_bounds__(64) void vec4_kernel(
    const float* __restrict__ pqw, const float* __restrict__ pkw,
    const float* __restrict__ pe, const float* __restrict__ srow_b,
    float* __restrict__ bq, float* __restrict__ bk,
    float* __restrict__ tq_b, float* __restrict__ tk_b)
{
  int o = blockIdx.x, which = blockIdx.y, lane = threadIdx.x;
  const float* w = ((which & 1) == 0) ? pqw + (size_t)o * 512 : pkw + (size_t)o * 512;
  const float* v = (which < 2) ? pe : srow_b;
  float s = 0.f;
  for (int c = lane; c < 512; c += 64) s += w[c] * v[c];
#pragma unroll
  for (int off = 32; off > 0; off >>= 1) s += __shfl_down(s, off, 64);
  if (lane == 0) {
    float* dst = (which == 0) ? bq : (which == 1) ? bk : (which == 2) ? tq_b : tk_b;
    dst[o] = s;
  }
}

// PqG[h][r][d] = sum_c Pq[h*128+r,c] * G[c,d]. grid (32 dt, 8 rt, 4 h)
__global__ __launch_bounds__(256) void posA_kernel(
    const float* __restrict__ pqw, const float* __restrict__ Gb,
    float* __restrict__ PqG)
{
  int tx = threadIdx.x & 15, ty = threadIdx.x >> 4;
  int h = blockIdx.z;
  int r = blockIdx.y * 16 + ty;
  int d = blockIdx.x * 16 + tx;
  const float* wr = pqw + (size_t)(h * 128 + r) * 512;
  float s = 0.f;
#pragma unroll 4
  for (int c = 0; c < 512; c++) s += wr[c] * Gb[(size_t)c * 512 + d];
  PqG[((size_t)h * 128 + r) * 512 + d] = s;
}

// lgp[h][r][s] = PqG[h,r,:]·Pk[h*128+s,:] + tq*bk + bq*tk + N*bq*bk
__global__ __launch_bounds__(256) void posB_kernel(
    const float* __restrict__ PqG, const float* __restrict__ pkw,
    const float* __restrict__ bq, const float* __restrict__ bk,
    const float* __restrict__ tq_b, const float* __restrict__ tk_b,
    float* __restrict__ lgp)
{
  int tx = threadIdx.x & 15, ty = threadIdx.x >> 4;
  int h = blockIdx.z;
  int r = blockIdx.y * 16 + ty;
  int s = blockIdx.x * 16 + tx;
  int gr = h * 128 + r, gs = h * 128 + s;
  const float* ar = PqG + (size_t)gr * 512;
  const float* kr = pkw + (size_t)gs * 512;
  float acc = 0.f;
#pragma unroll 4
  for (int c = 0; c < 512; c++) acc += ar[c] * kr[c];
  acc += tq_b[gr] * bk[gs] + bq[gr] * tk_b[gs] + 16384.f * bq[gr] * bk[gs];
  lgp[(size_t)h * 16384 + r * 128 + s] = acc;
}

// comb = softmax(lgs/(rq*rk)*t) + softmax(lgp). grid 512 (h,c), 128 thr (d)
__global__ __launch_bounds__(128) void smx_kernel(
    const float* __restrict__ lgs_b, const float* __restrict__ lgp,
    const float* __restrict__ n2q_b, const float* __restrict__ n2k_b,
    const float* __restrict__ temp, float* __restrict__ comb)
{
  int c = blockIdx.x & 127, h = blockIdx.x >> 7;
  int d = threadIdx.x;
  float rq = fmaxf(sqrtf(n2q_b[h * 128 + c]), 1e-12f);
  float rk = fmaxf(sqrtf(n2k_b[h * 128 + d]), 1e-12f);
  float s0 = lgs_b[(size_t)h * 16384 + c * 128 + d] / (rq * rk) * temp[h];
  float s1 = lgp[(size_t)h * 16384 + c * 128 + d];
  __shared__ float sh[128];
  sh[d] = s0; __syncthreads();
  for (int s = 64; s > 0; s >>= 1) { if (d < s) sh[d] = fmaxf(sh[d], sh[d + s]); __syncthreads(); }
  float m0 = sh[0]; __syncthreads();
  float e0 = __expf(s0 - m0);
  sh[d] = e0; __syncthreads();
  for (int s = 64; s > 0; s >>= 1) { if (d < s) sh[d] += sh[d + s]; __syncthreads(); }
  float z0 = sh[0]; __syncthreads();
  sh[d] = s1; __syncthreads();
  for (int s = 64; s > 0; s >>= 1) { if (d < s) sh[d] = fmaxf(sh[d], sh[d + s]); __syncthreads(); }
  float m1 = sh[0]; __syncthreads();
  float e1 = __expf(s1 - m1);
  sh[d] = e1; __syncthreads();
  for (int s = 64; s > 0; s >>= 1) { if (d < s) sh[d] += sh[d + s]; __syncthreads(); }
  float z1 = sh[0];
  comb[(size_t)h * 16384 + c * 128 + d] = e0 / z0 + e1 / z1;
}

// Mb[o][h*128+d] = sum_r proj_w[o, h*128+r] * comb[h][r][d]. grid (8,32,4)
__global__ __launch_bounds__(256) void mb_kernel(
    const float* __restrict__ proj_w, const float* __restrict__ comb,
    f16_t* __restrict__ Mb)
{
  int tx = threadIdx.x & 15, ty = threadIdx.x >> 4;
  int h = blockIdx.z;
  int o = blockIdx.y * 16 + ty;
  int d = blockIdx.x * 16 + tx;
  const float* pw = proj_w + (size_t)o * 512 + h * 128;
  const float* cm = comb + (size_t)h * 16384 + d;
  float s = 0.f;
#pragma unroll 4
  for (int r = 0; r < 128; r++) s += pw[r] * cm[(size_t)r * 128];
  Mb[(size_t)o * 512 + h * 128 + d] = (f16_t)s;
}

__global__ __launch_bounds__(256) void castw_kernel(
    const float* __restrict__ q_w, const float* __restrict__ kv_w,
    f16_t* __restrict__ Wq, f16_t* __restrict__ Wkv)
{
  int i = blockIdx.x * 256 + threadIdx.x;
  if (i < 262144) Wq[i] = (f16_t)q_w[i];
  else Wkv[i - 262144] = (f16_t)kv_w[i - 262144];
}

__global__ __launch_bounds__(256) void zero_kernel(float* __restrict__ p, long n) {
  long i = (long)blockIdx.x * 256 + threadIdx.x;
  if (i < n) p[i] = 0.f;
}

extern "C" void kernel_launch(void* const* d_in, const int* in_sizes, int n_in,
                              void* d_out, int out_size, void* d_ws, size_t ws_size,
                              hipStream_t stream) {
  const float* x      = (const float*)d_in[0];
  const float* y      = (const float*)d_in[1];
  const float* temp   = (const float*)d_in[2];
  const float* q_w    = (const float*)d_in[3];
  const float* q_dw   = (const float*)d_in[4];
  const float* kv_w   = (const float*)d_in[5];
  const float* kv_dw  = (const float*)d_in[6];
  const float* proj_w = (const float*)d_in[7];
  const float* pe     = (const float*)d_in[8];
  const float* pqw    = (const float*)d_in[9];
  const float* pkw    = (const float*)d_in[10];

  const size_t MB = 1ull << 20;
  const size_t N = NDIM;
  char* Wb = (char*)d_ws;
  f16_t* Abuf = (f16_t*)(Wb);             // xc -> q
  f16_t* Bbuf = (f16_t*)(Wb + 16 * MB);   // xT -> vT
  f16_t* Cbuf = (f16_t*)(Wb + 32 * MB);   // yT -> v
  f16_t* Dbuf = (f16_t*)(Wb + 48 * MB);   // q_pre -> k
  char* SM = Wb + 64 * MB;
  float* G    = (float*)(SM);                       // [2][512][512]
  float* lgs  = (float*)(SM + 2 * MB);              // [2][4][16384]
  float* n2q  = (float*)(SM + 2 * MB + 512 * 1024); // [2][512]
  float* n2k  = n2q + 1024;
  float* srow = n2k + 1024;                         // [2][512]
  float* bq   = (float*)(SM + 3 * MB);
  float* bk   = bq + 512;
  float* tq   = bk + 512;                           // [2][512]
  float* tk   = tq + 1024;
  f16_t* Wq   = (f16_t*)(SM + 3 * MB + 16 * 1024);
  f16_t* Wkv  = (f16_t*)(SM + 3 * MB + 16 * 1024 + 512 * 1024);
  float* PqG  = (float*)(SM + 5 * MB);              // [4][128][512]
  float* lgp  = (float*)(SM + 6 * MB);              // [4][16384]
  float* comb = (float*)(SM + 6 * MB + 256 * 1024); // [4][16384]
  f16_t* Mb   = (f16_t*)(SM + 6 * MB + 512 * 1024); // [512][512]
  // total ws use: 71 MB

  // zero atomic targets: G, lgs, n2q, n2k, srow
  zero_kernel<<<2572, 256, 0, stream>>>((float*)SM, 658432L);
  castw_kernel<<<3072, 256, 0, stream>>>(q_w, kv_w, Wq, Wkv);

  for (int b = 0; b < 2; b++) {
    const float* xb = x + (size_t)b * 512 * N;
    const float* yb = y + (size_t)b * 512 * N;
    float* srow_b = srow + b * 512;
    float* Gb = G + (size_t)b * 512 * 512;
    float* lgs_b = lgs + (size_t)b * 4 * 16384;
    f16_t* kvp = (f16_t*)d_out + (size_t)b * 1024 * N;   // scratch in d_out
    float* outb = (float*)d_out + (size_t)b * 512 * N;

    cast_x_kernel<<<dim3(64, 512), 256, 0, stream>>>(xb, Abuf, srow_b);
    vec4_kernel<<<dim3(512, 4), 64, 0, stream>>>(pqw, pkw, pe, srow_b,
                                                 bq, bk, tq + b * 512, tk + b * 512);
    gram_kernel<<<dim3(16, 16), 256, 0, stream>>>(Abuf, Gb);
    transpose2_kernel<<<dim3(512, 16, 2), 256, 0, stream>>>(xb, yb, Bbuf, Cbuf);
    // q_pre = Wq @ xT^T
    gemm_bt_kernel<0, f16_t><<<dim3(128, 4), 256, 0, stream>>>(
        Wq, 512, Bbuf, 512, Dbuf, (int)N, 512);
    // kv_pre = Wkv @ yT^T  (staged in d_out)
    gemm_bt_kernel<0, f16_t><<<dim3(128, 8), 256, 0, stream>>>(
        Wkv, 512, Cbuf, 512, kvp, (int)N, 512);
    // dwconv q (+||q row||^2), q -> Abuf (xc dead after gram)
    dwconv_kernel<<<dim3(2, 512), 256, 0, stream>>>(
        Dbuf, q_dw, Abuf, (f16_t*)nullptr, 512, n2q + b * 512);
    // dwconv kv: k -> Dbuf (q_pre dead), v -> Cbuf (yT dead)
    dwconv_kernel<<<dim3(2, 1024), 256, 0, stream>>>(
        kvp, kv_dw, Dbuf, Cbuf, 512, n2k + b * 512);
    // vT -> Bbuf (xT dead)
    transpose_f16_kernel<<<dim3(512, 16), 256, 0, stream>>>(Cbuf, Bbuf);
    // S-branch raw logits
    qk_kernel<<<dim3(32, 4), 256, 0, stream>>>(Abuf, Dbuf, lgs_b);
    // pos branch via Gram
    posA_kernel<<<dim3(32, 8, 4), 256, 0, stream>>>(pqw, Gb, PqG);
    posB_kernel<<<dim3(8, 8, 4), 256, 0, stream>>>(PqG, pkw, bq, bk,
                                                   tq + b * 512, tk + b * 512, lgp);
    smx_kernel<<<512, 128, 0, stream>>>(lgs_b, lgp, n2q + b * 512, n2k + b * 512,
                                        temp, comb);
    mb_kernel<<<dim3(8, 32, 4), 256, 0, stream>>>(proj_w, comb, Mb);
    // out_b = Mb @ vT^T  (overwrites kvp region, which is dead)
    gemm_bt_kernel<1, float><<<dim3(128, 4), 256, 0, stream>>>(
        Mb, 512, Bbuf, 512, outb, (int)N, 512);
  }

  (void)in_sizes; (void)n_in; (void)out_size; (void)ws_size;
}

// Round 4
// 658.862 us; speedup vs baseline: 1.9139x; 1.2101x over previous
//
#include <hip/hip_runtime.h>

// CFA channel-attention, B=2, C=512, H=W=128, HEADS=4, gfx950.
// f32 in/out; internal fp16 MFMA + f32 accumulation.
// Per-batch pipeline; ws footprint 71 MB; kv_pre staged inside d_out.

typedef _Float16 f16_t;
typedef __attribute__((ext_vector_type(4))) _Float16 f16x4;
typedef __attribute__((ext_vector_type(8))) _Float16 f16x8;
typedef __attribute__((ext_vector_type(4))) float f32x4;

#define NDIM 16384

__device__ __forceinline__ void gload_lds16(const void* g, void* l) {
  __builtin_amdgcn_global_load_lds((__attribute__((address_space(1))) void*)g,
                                   (__attribute__((address_space(3))) void*)l, 16, 0, 0);
}

// C = A * B^T ; A [M,K] row-major f16, B [Ncols,K] row-major f16. 128x128 tile,
// 4 waves 2x2, each 64x64 via 4x4 mfma_f32_16x16x32_f16.
// EPI: 0 = store f16, 1 = store f32, 2 = atomicAdd f32 (split-K).
template<int EPI>
__device__ __forceinline__ void gemm_core_128(
    const f16_t* __restrict__ At, int lda,
    const f16_t* __restrict__ Bt, int ldb,
    void* __restrict__ Ct, int ldc, int K)
{
  __shared__ f16_t As[128 * 32];
  __shared__ f16_t Bs[128 * 32];
  const int tid = threadIdx.x;
  const int lane = tid & 63;
  const int wave = tid >> 6;
  const int wm = (wave >> 1) * 64;
  const int wn = (wave & 1) * 64;
  const int lr = lane & 15;
  const int lq = lane >> 4;

  const f16_t* gA0 = At + (size_t)(tid >> 2) * lda + (tid & 3) * 8;
  const f16_t* gA1 = At + (size_t)((tid + 256) >> 2) * lda + (tid & 3) * 8;
  const f16_t* gB0 = Bt + (size_t)(tid >> 2) * ldb + (tid & 3) * 8;
  const f16_t* gB1 = Bt + (size_t)((tid + 256) >> 2) * ldb + (tid & 3) * 8;
  f16_t* lA0 = &As[tid * 8];
  f16_t* lA1 = &As[(tid + 256) * 8];
  f16_t* lB0 = &Bs[tid * 8];
  f16_t* lB1 = &Bs[(tid + 256) * 8];

  f32x4 acc[4][4] = {};

  for (int kk = 0; kk < K; kk += 32) {
    if (kk) __syncthreads();
    gload_lds16(gA0 + kk, lA0);
    gload_lds16(gA1 + kk, lA1);
    gload_lds16(gB0 + kk, lB0);
    gload_lds16(gB1 + kk, lB1);
    __syncthreads();

    f16x8 af[4], bfr[4];
#pragma unroll
    for (int i = 0; i < 4; i++) {
      af[i]  = *(const f16x8*)&As[(wm + i * 16 + lr) * 32 + lq * 8];
      bfr[i] = *(const f16x8*)&Bs[(wn + i * 16 + lr) * 32 + lq * 8];
    }
#pragma unroll
    for (int i = 0; i < 4; i++)
#pragma unroll
      for (int j = 0; j < 4; j++)
        acc[i][j] = __builtin_amdgcn_mfma_f32_16x16x32_f16(af[i], bfr[j], acc[i][j], 0, 0, 0);
  }

  // C/D layout: col = lane&15, row = (lane>>4)*4 + reg   [m89-verified]
#pragma unroll
  for (int i = 0; i < 4; i++)
#pragma unroll
    for (int j = 0; j < 4; j++)
#pragma unroll
      for (int r = 0; r < 4; r++) {
        int row = wm + i * 16 + lq * 4 + r;
        int col = wn + j * 16 + lr;
        float v = acc[i][j][r];
        if (EPI == 0)      ((f16_t*)Ct)[(size_t)row * ldc + col] = (f16_t)v;
        else if (EPI == 1) ((float*)Ct)[(size_t)row * ldc + col] = v;
        else               atomicAdd(&((float*)Ct)[(size_t)row * ldc + col], v);
      }
}

template<int EPI, typename CT>
__global__ __launch_bounds__(256) void gemm_bt_kernel(
    const f16_t* __restrict__ A, int lda, const f16_t* __restrict__ B, int ldb,
    CT* __restrict__ C, int ldc, int K)
{
  const f16_t* At = A + (size_t)blockIdx.y * 128 * lda;
  const f16_t* Bt = B + (size_t)blockIdx.x * 128 * ldb;
  CT* Ct = C + (size_t)blockIdx.y * 128 * ldc + (size_t)blockIdx.x * 128;
  gemm_core_128<EPI>(At, lda, Bt, ldb, (void*)Ct, ldc, K);
}

// Gram: G += xc * xc^T, split-K 16x1024, grid (16 ks, 16 tiles)
__global__ __launch_bounds__(256) void gram_kernel(
    const f16_t* __restrict__ xc, float* __restrict__ Gb)
{
  int ks = blockIdx.x, t = blockIdx.y;
  int ty = t >> 2, tx = t & 3;
  const f16_t* At = xc + (size_t)ty * 128 * NDIM + ks * 1024;
  const f16_t* Bt = xc + (size_t)tx * 128 * NDIM + ks * 1024;
  float* Ct = Gb + (size_t)ty * 128 * 512 + tx * 128;
  gemm_core_128<2>(At, NDIM, Bt, NDIM, Ct, 512, 1024);
}

// S-branch raw QK^T, split-K=32 (K=512 each), grid (32 ks, 4 h)
__global__ __launch_bounds__(256) void qk_kernel(
    const f16_t* __restrict__ q, const f16_t* __restrict__ k,
    float* __restrict__ lgs_b)
{
  int ks = blockIdx.x, h = blockIdx.y;
  const f16_t* At = q + (size_t)h * 128 * NDIM + ks * 512;
  const f16_t* Bt = k + (size_t)h * 128 * NDIM + ks * 512;
  float* Ct = lgs_b + (size_t)h * 16384;
  gemm_core_128<2>(At, NDIM, Bt, NDIM, Ct, 128, 512);
}

// f32 [512][NDIM] -> f16 [NDIM][512] transposed, 64x64 tiles.
// grid (256, 8, 2); z selects (x->dx) or (y->dy).
__global__ __launch_bounds__(256) void transpose2_kernel(
    const float* __restrict__ sx, const float* __restrict__ sy,
    f16_t* __restrict__ dx, f16_t* __restrict__ dy)
{
  const float* src = blockIdx.z ? sy : sx;
  f16_t* dst = blockIdx.z ? dy : dx;
  __shared__ f16_t tile[64][72];
  const int t = threadIdx.x;
  const int r0 = blockIdx.y * 64, c0 = blockIdx.x * 64;
  {
    int tx = t & 15, ty = t >> 4;
#pragma unroll
    for (int k = 0; k < 4; k++) {
      int r = ty + k * 16;
      f32x4 v = *(const f32x4*)(src + (size_t)(r0 + r) * NDIM + c0 + tx * 4);
      f16x4 o = { (f16_t)v[0], (f16_t)v[1], (f16_t)v[2], (f16_t)v[3] };
      *(f16x4*)&tile[r][tx * 4] = o;
    }
  }
  __syncthreads();
  {
    int j0 = t >> 3, cg = (t & 7) * 8;
#pragma unroll
    for (int k = 0; k < 2; k++) {
      int j = j0 + k * 32;
      f16x8 o;
#pragma unroll
      for (int i = 0; i < 8; i++) o[i] = tile[cg + i][j];
      *(f16x8*)(dst + (size_t)(c0 + j) * 512 + r0 + cg) = o;
    }
  }
}

// f16 [512][NDIM] -> f16 [NDIM][512], 64x64 tiles. grid (256, 8)
__global__ __launch_bounds__(256) void transpose_f16_kernel(
    const f16_t* __restrict__ src, f16_t* __restrict__ dst)
{
  __shared__ f16_t tile[64][72];
  const int t = threadIdx.x;
  const int r0 = blockIdx.y * 64, c0 = blockIdx.x * 64;
  {
    int tx = t & 7, ty = t >> 3;   // 8 x 32
#pragma unroll
    for (int k = 0; k < 2; k++) {
      int r = ty + k * 32;
      f16x8 v = *(const f16x8*)(src + (size_t)(r0 + r) * NDIM + c0 + tx * 8);
      *(f16x8*)&tile[r][tx * 8] = v;
    }
  }
  __syncthreads();
  {
    int j0 = t >> 3, cg = (t & 7) * 8;
#pragma unroll
    for (int k = 0; k < 2; k++) {
      int j = j0 + k * 32;
      f16x8 o;
#pragma unroll
      for (int i = 0; i < 8; i++) o[i] = tile[cg + i][j];
      *(f16x8*)(dst + (size_t)(c0 + j) * 512 + r0 + cg) = o;
    }
  }
}

// x (f32 [512][N]) -> xc (f16) + fused row sums. grid (8, 512), 8 elem/thr.
__global__ __launch_bounds__(256) void cast_x_kernel(
    const float* __restrict__ xb, f16_t* __restrict__ xc, float* __restrict__ srow_b)
{
  const int c = blockIdx.y;
  const int base = blockIdx.x * 2048 + threadIdx.x * 8;
  const float* src = xb + (size_t)c * NDIM + base;
  f32x4 a = *(const f32x4*)src;
  f32x4 b = *(const f32x4*)(src + 4);
  f16x8 o = { (f16_t)a[0], (f16_t)a[1], (f16_t)a[2], (f16_t)a[3],
              (f16_t)b[0], (f16_t)b[1], (f16_t)b[2], (f16_t)b[3] };
  *(f16x8*)(xc + (size_t)c * NDIM + base) = o;
  float s = a[0] + a[1] + a[2] + a[3] + b[0] + b[1] + b[2] + b[3];
#pragma unroll
  for (int off = 32; off > 0; off >>= 1) s += __shfl_down(s, off, 64);
  __shared__ float ws[4];
  if ((threadIdx.x & 63) == 0) ws[threadIdx.x >> 6] = s;
  __syncthreads();
  if (threadIdx.x == 0) atomicAdd(&srow_b[c], ws[0] + ws[1] + ws[2] + ws[3]);
}

// Depthwise 3x3 SAME, register-tiled + vectorized. grid (2 row-halves, C).
__global__ __launch_bounds__(256) void dwconv_kernel(
    const f16_t* __restrict__ in, const float* __restrict__ w,
    f16_t* __restrict__ outA, f16_t* __restrict__ outB,
    int splitC, float* __restrict__ norm2)
{
  const int c = blockIdx.y;
  const int t = threadIdx.x;
  const int xs = (t & 15) * 8;
  const int h0 = blockIdx.x * 64 + (t >> 4) * 4;
  const f16_t* src = in + (size_t)c * NDIM;
  const float* wc = w + c * 9;
  float w00 = wc[0], w01 = wc[1], w02 = wc[2];
  float w10 = wc[3], w11 = wc[4], w12 = wc[5];
  float w20 = wc[6], w21 = wc[7], w22 = wc[8];

  float rows[6][10];
#pragma unroll
  for (int i = 0; i < 6; i++) {
    int hh = h0 - 1 + i;
    int hc = hh < 0 ? 0 : (hh > 127 ? 127 : hh);
    f16x8 v = *(const f16x8*)(src + hc * 128 + xs);
    float l = __shfl_up((float)v[7], 1, 64);
    float r = __shfl_down((float)v[0], 1, 64);
    if ((t & 15) == 0) l = 0.f;
    if ((t & 15) == 15) r = 0.f;
    bool oob = (hh < 0) || (hh > 127);
    rows[i][0] = oob ? 0.f : l;
    rows[i][9] = oob ? 0.f : r;
#pragma unroll
    for (int j = 0; j < 8; j++) rows[i][1 + j] = oob ? 0.f : (float)v[j];
  }

  float s2 = 0.f;
  f16_t* dst = (c < splitC) ? outA + (size_t)c * NDIM
                            : outB + (size_t)(c - splitC) * NDIM;
#pragma unroll
  for (int i = 0; i < 4; i++) {
    f16x8 o;
#pragma unroll
    for (int j = 0; j < 8; j++) {
      float a = w00 * rows[i][j]     + w01 * rows[i][j + 1]     + w02 * rows[i][j + 2]
              + w10 * rows[i + 1][j] + w11 * rows[i + 1][j + 1] + w12 * rows[i + 1][j + 2]
              + w20 * rows[i + 2][j] + w21 * rows[i + 2][j + 1] + w22 * rows[i + 2][j + 2];
      o[j] = (f16_t)a;
      s2 += a * a;
    }
    *(f16x8*)(dst + (h0 + i) * 128 + xs) = o;
  }

  if (c < splitC) {
#pragma unroll
    for (int off = 32; off > 0; off >>= 1) s2 += __shfl_down(s2, off, 64);
    __shared__ float ws[4];
    if ((t & 63) == 0) ws[t >> 6] = s2;
    __syncthreads();
    if (t == 0) atomicAdd(&norm2[c], ws[0] + ws[1] + ws[2] + ws[3]);
  }
}

// bq = Pq@pe, bk = Pk@pe, tq = Pq@srow, tk = Pk@srow. grid (512 o, 4 which)
__global__ __launch_bounds__(64) void vec4_kernel(
    const float* __restrict__ pqw, const float* __restrict__ pkw,
    const float* __restrict__ pe, const float* __restrict__ srow_b,
    float* __restrict__ bq, float* __restrict__ bk,
    float* __restrict__ tq_b, float* __restrict__ tk_b)
{
  int o = blockIdx.x, which = blockIdx.y, lane = threadIdx.x;
  const float* w = ((which & 1) == 0) ? pqw + (size_t)o * 512 : pkw + (size_t)o * 512;
  const float* v = (which < 2) ? pe : srow_b;
  float s = 0.f;
  for (int c = lane; c < 512; c += 64) s += w[c] * v[c];
#pragma unroll
  for (int off = 32; off > 0; off >>= 1) s += __shfl_down(s, off, 64);
  if (lane == 0) {
    float* dst = (which == 0) ? bq : (which == 1) ? bk : (which == 2) ? tq_b : tk_b;
    dst[o] = s;
  }
}

// PqG[h][r][d] = sum_c Pq[h*128+r,c] * G[c,d]. grid (32 dt, 8 rt, 4 h)
__global__ __launch_bounds__(256) void posA_kernel(
    const float* __restrict__ pqw, const float* __restrict__ Gb,
    float* __restrict__ PqG)
{
  int tx = threadIdx.x & 15, ty = threadIdx.x >> 4;
  int h = blockIdx.z;
  int r = blockIdx.y * 16 + ty;
  int d = blockIdx.x * 16 + tx;
  const float* wr = pqw + (size_t)(h * 128 + r) * 512;
  float s = 0.f;
#pragma unroll 4
  for (int c = 0; c < 512; c++) s += wr[c] * Gb[(size_t)c * 512 + d];
  PqG[((size_t)h * 128 + r) * 512 + d] = s;
}

// lgp[h][r][s] = PqG[h,r,:]·Pk[h*128+s,:] + tq*bk + bq*tk + N*bq*bk
__global__ __launch_bounds__(256) void posB_kernel(
    const float* __restrict__ PqG, const float* __restrict__ pkw,
    const float* __restrict__ bq, const float* __restrict__ bk,
    const float* __restrict__ tq_b, const float* __restrict__ tk_b,
    float* __restrict__ lgp)
{
  int tx = threadIdx.x & 15, ty = threadIdx.x >> 4;
  int h = blockIdx.z;
  int r = blockIdx.y * 16 + ty;
  int s = blockIdx.x * 16 + tx;
  int gr = h * 128 + r, gs = h * 128 + s;
  const float* ar = PqG + (size_t)gr * 512;
  const float* kr = pkw + (size_t)gs * 512;
  float acc = 0.f;
#pragma unroll 4
  for (int c = 0; c < 512; c++) acc += ar[c] * kr[c];
  acc += tq_b[gr] * bk[gs] + bq[gr] * tk_b[gs] + 16384.f * bq[gr] * bk[gs];
  lgp[(size_t)h * 16384 + r * 128 + s] = acc;
}

// comb = softmax(lgs/(rq*rk)*t) + softmax(lgp). One wave per (h,c) row,
// butterfly reductions, zero barriers. grid 512, 64 thr.
__global__ __launch_bounds__(64) void smx_kernel(
    const float* __restrict__ lgs_b, const float* __restrict__ lgp,
    const float* __restrict__ n2q_b, const float* __restrict__ n2k_b,
    const float* __restrict__ temp, float* __restrict__ comb)
{
  int c = blockIdx.x & 127, h = blockIdx.x >> 7;
  int l = threadIdx.x;
  int d0 = l, d1 = l + 64;
  float rq = fmaxf(sqrtf(n2q_b[h * 128 + c]), 1e-12f);
  float rk0 = fmaxf(sqrtf(n2k_b[h * 128 + d0]), 1e-12f);
  float rk1 = fmaxf(sqrtf(n2k_b[h * 128 + d1]), 1e-12f);
  float t = temp[h];
  size_t base = (size_t)h * 16384 + c * 128;
  float s00 = lgs_b[base + d0] / (rq * rk0) * t;
  float s01 = lgs_b[base + d1] / (rq * rk1) * t;
  float s10 = lgp[base + d0];
  float s11 = lgp[base + d1];

  float m0 = fmaxf(s00, s01);
#pragma unroll
  for (int msk = 32; msk > 0; msk >>= 1) m0 = fmaxf(m0, __shfl_xor(m0, msk, 64));
  float e00 = __expf(s00 - m0), e01 = __expf(s01 - m0);
  float z0 = e00 + e01;
#pragma unroll
  for (int msk = 32; msk > 0; msk >>= 1) z0 += __shfl_xor(z0, msk, 64);

  float m1 = fmaxf(s10, s11);
#pragma unroll
  for (int msk = 32; msk > 0; msk >>= 1) m1 = fmaxf(m1, __shfl_xor(m1, msk, 64));
  float e10 = __expf(s10 - m1), e11 = __expf(s11 - m1);
  float z1 = e10 + e11;
#pragma unroll
  for (int msk = 32; msk > 0; msk >>= 1) z1 += __shfl_xor(z1, msk, 64);

  comb[base + d0] = e00 / z0 + e10 / z1;
  comb[base + d1] = e01 / z0 + e11 / z1;
}

// Mb[o][h*128+d] = sum_r proj_w[o, h*128+r] * comb[h][r][d]. grid (8,32,4)
__global__ __launch_bounds__(256) void mb_kernel(
    const float* __restrict__ proj_w, const float* __restrict__ comb,
    f16_t* __restrict__ Mb)
{
  int tx = threadIdx.x & 15, ty = threadIdx.x >> 4;
  int h = blockIdx.z;
  int o = blockIdx.y * 16 + ty;
  int d = blockIdx.x * 16 + tx;
  const float* pw = proj_w + (size_t)o * 512 + h * 128;
  const float* cm = comb + (size_t)h * 16384 + d;
  float s = 0.f;
#pragma unroll 4
  for (int r = 0; r < 128; r++) s += pw[r] * cm[(size_t)r * 128];
  Mb[(size_t)o * 512 + h * 128 + d] = (f16_t)s;
}

__global__ __launch_bounds__(256) void castw_kernel(
    const float* __restrict__ q_w, const float* __restrict__ kv_w,
    f16_t* __restrict__ Wq, f16_t* __restrict__ Wkv)
{
  int i = blockIdx.x * 256 + threadIdx.x;
  if (i < 262144) Wq[i] = (f16_t)q_w[i];
  else Wkv[i - 262144] = (f16_t)kv_w[i - 262144];
}

__global__ __launch_bounds__(256) void zero_kernel(float* __restrict__ p, long n) {
  long i = (long)blockIdx.x * 256 + threadIdx.x;
  if (i < n) p[i] = 0.f;
}

extern "C" void kernel_launch(void* const* d_in, const int* in_sizes, int n_in,
                              void* d_out, int out_size, void* d_ws, size_t ws_size,
                              hipStream_t stream) {
  const float* x      = (const float*)d_in[0];
  const float* y      = (const float*)d_in[1];
  const float* temp   = (const float*)d_in[2];
  const float* q_w    = (const float*)d_in[3];
  const float* q_dw   = (const float*)d_in[4];
  const float* kv_w   = (const float*)d_in[5];
  const float* kv_dw  = (const float*)d_in[6];
  const float* proj_w = (const float*)d_in[7];
  const float* pe     = (const float*)d_in[8];
  const float* pqw    = (const float*)d_in[9];
  const float* pkw    = (const float*)d_in[10];

  const size_t MB = 1ull << 20;
  const size_t N = NDIM;
  char* Wb = (char*)d_ws;
  f16_t* Abuf = (f16_t*)(Wb);             // xc -> q
  f16_t* Bbuf = (f16_t*)(Wb + 16 * MB);   // xT -> vT
  f16_t* Cbuf = (f16_t*)(Wb + 32 * MB);   // yT -> v
  f16_t* Dbuf = (f16_t*)(Wb + 48 * MB);   // q_pre -> k
  char* SM = Wb + 64 * MB;
  float* G    = (float*)(SM);                       // [2][512][512]
  float* lgs  = (float*)(SM + 2 * MB);              // [2][4][16384]
  float* n2q  = (float*)(SM + 2 * MB + 512 * 1024); // [2][512]
  float* n2k  = n2q + 1024;
  float* srow = n2k + 1024;                         // [2][512]
  float* bq   = (float*)(SM + 3 * MB);
  float* bk   = bq + 512;
  float* tq   = bk + 512;                           // [2][512]
  float* tk   = tq + 1024;
  f16_t* Wq   = (f16_t*)(SM + 3 * MB + 16 * 1024);
  f16_t* Wkv  = (f16_t*)(SM + 3 * MB + 16 * 1024 + 512 * 1024);
  float* PqG  = (float*)(SM + 5 * MB);              // [4][128][512]
  float* lgp  = (float*)(SM + 6 * MB);              // [4][16384]
  float* comb = (float*)(SM + 6 * MB + 256 * 1024); // [4][16384]
  f16_t* Mb   = (f16_t*)(SM + 6 * MB + 512 * 1024); // [512][512]
  // total ws use: 71 MB

  // zero atomic targets: G, lgs, n2q, n2k, srow
  zero_kernel<<<2572, 256, 0, stream>>>((float*)SM, 658432L);
  castw_kernel<<<3072, 256, 0, stream>>>(q_w, kv_w, Wq, Wkv);

  for (int b = 0; b < 2; b++) {
    const float* xb = x + (size_t)b * 512 * N;
    const float* yb = y + (size_t)b * 512 * N;
    float* srow_b = srow + b * 512;
    float* Gb = G + (size_t)b * 512 * 512;
    float* lgs_b = lgs + (size_t)b * 4 * 16384;
    f16_t* kvp = (f16_t*)d_out + (size_t)b * 1024 * N;   // scratch in d_out
    float* outb = (float*)d_out + (size_t)b * 512 * N;

    cast_x_kernel<<<dim3(8, 512), 256, 0, stream>>>(xb, Abuf, srow_b);
    vec4_kernel<<<dim3(512, 4), 64, 0, stream>>>(pqw, pkw, pe, srow_b,
                                                 bq, bk, tq + b * 512, tk + b * 512);
    gram_kernel<<<dim3(16, 16), 256, 0, stream>>>(Abuf, Gb);
    transpose2_kernel<<<dim3(256, 8, 2), 256, 0, stream>>>(xb, yb, Bbuf, Cbuf);
    // q_pre = Wq @ xT^T
    gemm_bt_kernel<0, f16_t><<<dim3(128, 4), 256, 0, stream>>>(
        Wq, 512, Bbuf, 512, Dbuf, (int)N, 512);
    // kv_pre = Wkv @ yT^T  (staged in d_out)
    gemm_bt_kernel<0, f16_t><<<dim3(128, 8), 256, 0, stream>>>(
        Wkv, 512, Cbuf, 512, kvp, (int)N, 512);
    // dwconv q (+||q row||^2), q -> Abuf (xc dead after gram)
    dwconv_kernel<<<dim3(2, 512), 256, 0, stream>>>(
        Dbuf, q_dw, Abuf, (f16_t*)nullptr, 512, n2q + b * 512);
    // dwconv kv: k -> Dbuf (q_pre dead), v -> Cbuf (yT dead)
    dwconv_kernel<<<dim3(2, 1024), 256, 0, stream>>>(
        kvp, kv_dw, Dbuf, Cbuf, 512, n2k + b * 512);
    // vT -> Bbuf (xT dead)
    transpose_f16_kernel<<<dim3(256, 8), 256, 0, stream>>>(Cbuf, Bbuf);
    // S-branch raw logits
    qk_kernel<<<dim3(32, 4), 256, 0, stream>>>(Abuf, Dbuf, lgs_b);
    // pos branch via Gram
    posA_kernel<<<dim3(32, 8, 4), 256, 0, stream>>>(pqw, Gb, PqG);
    posB_kernel<<<dim3(8, 8, 4), 256, 0, stream>>>(PqG, pkw, bq, bk,
                                                   tq + b * 512, tk + b * 512, lgp);
    smx_kernel<<<512, 64, 0, stream>>>(lgs_b, lgp, n2q + b * 512, n2k + b * 512,
                                       temp, comb);
    mb_kernel<<<dim3(8, 32, 4), 256, 0, stream>>>(proj_w, comb, Mb);
    // out_b = Mb @ vT^T  (overwrites kvp region, which is dead)
    gemm_bt_kernel<1, float><<<dim3(128, 4), 256, 0, stream>>>(
        Mb, 512, Bbuf, 512, outb, (int)N, 512);
  }

  (void)in_sizes; (void)n_in; (void)out_size; (void)ws_size;
}